// Round 3
// baseline (127.505 us; speedup 1.0000x reference)
//
#include <hip/hip_runtime.h>
#include <hip/hip_bf16.h>

#define A_N 256
#define F_N 256
#define C_N 32

// ---------------------------------------------------------------------------
// Kernel 1: LayerNorm + dual projections (+mask). One block per node.
// ---------------------------------------------------------------------------
__global__ __launch_bounds__(256) void ln_proj_kernel(
    const float* __restrict__ node_vec, const float* __restrict__ node_mask,
    const float* __restrict__ ln_scale, const float* __restrict__ ln_bias,
    const float* __restrict__ Wl, const float* __restrict__ bl,
    const float* __restrict__ Wr, const float* __restrict__ br,
    float* __restrict__ left, float* __restrict__ right) {
  const int a = blockIdx.x;
  const int t = threadIdx.x;
  __shared__ float sAct[F_N];
  __shared__ float sRed[8];
  __shared__ float sPl[8][C_N];
  __shared__ float sPr[8][C_N];

  float x = node_vec[a * F_N + t];

  // mean
  float s = x;
  for (int off = 32; off; off >>= 1) s += __shfl_down(s, off, 64);
  const int wave = t >> 6, lane = t & 63;
  if (lane == 0) sRed[wave] = s;
  __syncthreads();
  if (t == 0) sRed[4] = (sRed[0] + sRed[1] + sRed[2] + sRed[3]) * (1.0f / F_N);
  __syncthreads();
  const float mu = sRed[4];
  const float d = x - mu;

  // variance
  s = d * d;
  for (int off = 32; off; off >>= 1) s += __shfl_down(s, off, 64);
  if (lane == 0) sRed[wave] = s;
  __syncthreads();
  if (t == 0) {
    float v = (sRed[0] + sRed[1] + sRed[2] + sRed[3]) * (1.0f / F_N);
    sRed[5] = rsqrtf(v + 1e-5f);
  }
  __syncthreads();
  const float act = d * sRed[5] * ln_scale[t] + ln_bias[t];
  sAct[t] = act;
  __syncthreads();

  // projections: thread (seg, c) does a 32-long partial dot
  const int c = t & 31, seg = t >> 5;
  float pl = 0.f, pr = 0.f;
  const float* actp = &sAct[seg * 32];
#pragma unroll
  for (int j = 0; j < 32; ++j) {
    const float av = actp[j];
    const int widx = (seg * 32 + j) * C_N + c;
    pl = fmaf(av, Wl[widx], pl);
    pr = fmaf(av, Wr[widx], pr);
  }
  sPl[seg][c] = pl;
  sPr[seg][c] = pr;
  __syncthreads();
  if (t < C_N) {
    const float m = node_mask[a];
    float suml = bl[t], sumr = br[t];
#pragma unroll
    for (int sg = 0; sg < 8; ++sg) { suml += sPl[sg][t]; sumr += sPr[sg][t]; }
    left[a * C_N + t] = suml * m;
    right[a * C_N + t] = sumr * m;
  }
}

// ---------------------------------------------------------------------------
// Kernel 2: T[c][b][f] = sum_d right[b][d] * Wo[c*32+d][f]
// grid: (16 b-tiles, 32 c). Wo row-block (32x256 = 32KB) staged in LDS.
// ---------------------------------------------------------------------------
__global__ __launch_bounds__(256) void compT_kernel(
    const float* __restrict__ right, const float* __restrict__ Wo,
    float* __restrict__ T) {
  const int c = blockIdx.y;
  const int b0 = blockIdx.x * 16;
  const int f = threadIdx.x;
  __shared__ float sWo[C_N * F_N];  // 32 KB
  __shared__ float sR[16 * C_N];    // 2 KB

#pragma unroll
  for (int d = 0; d < C_N; ++d)
    sWo[d * F_N + f] = Wo[(c * C_N + d) * F_N + f];
  // right tile: 16*32 = 512 floats
  sR[f] = right[b0 * C_N + f];
  sR[256 + f] = right[b0 * C_N + 256 + f];
  __syncthreads();

#pragma unroll 4
  for (int b = 0; b < 16; ++b) {
    float acc = 0.f;
#pragma unroll
    for (int d = 0; d < C_N; ++d)
      acc = fmaf(sR[b * C_N + d], sWo[d * F_N + f], acc);
    T[c * (A_N * F_N) + (b0 + b) * F_N + f] = acc;
  }
}

// ---------------------------------------------------------------------------
// Kernel 3: out[a][b][f] = bo[f] + sum_c left[a][c] * T[c][b][f]
// grid: (4 a-tiles of 64, 256 b). 40 KB LDS -> 4 blocks/CU.
// ---------------------------------------------------------------------------
__global__ __launch_bounds__(256) void out_kernel(
    const float* __restrict__ left, const float* __restrict__ T,
    const float* __restrict__ bo, float* __restrict__ out) {
  const int b = blockIdx.y;
  const int a0 = blockIdx.x * 64;
  const int f = threadIdx.x;
  __shared__ float sT[C_N * F_N];  // 32 KB
  __shared__ float sL[64 * C_N];   // 8 KB

#pragma unroll
  for (int c = 0; c < C_N; ++c)
    sT[c * F_N + f] = T[c * (A_N * F_N) + b * F_N + f];
#pragma unroll
  for (int k = 0; k < 8; ++k) {
    const int idx = k * 256 + f;
    sL[idx] = left[a0 * C_N + idx];
  }
  const float biasf = bo[f];
  __syncthreads();

  for (int a = 0; a < 64; a += 4) {
    float acc0 = biasf, acc1 = biasf, acc2 = biasf, acc3 = biasf;
#pragma unroll
    for (int c = 0; c < C_N; ++c) {
      const float tv = sT[c * F_N + f];
      acc0 = fmaf(sL[(a + 0) * C_N + c], tv, acc0);
      acc1 = fmaf(sL[(a + 1) * C_N + c], tv, acc1);
      acc2 = fmaf(sL[(a + 2) * C_N + c], tv, acc2);
      acc3 = fmaf(sL[(a + 3) * C_N + c], tv, acc3);
    }
    const int base = (a0 + a) * (A_N * F_N) + b * F_N + f;
    out[base] = acc0;
    out[base + 1 * A_N * F_N] = acc1;
    out[base + 2 * A_N * F_N] = acc2;
    out[base + 3 * A_N * F_N] = acc3;
  }
}

extern "C" void kernel_launch(void* const* d_in, const int* in_sizes, int n_in,
                              void* d_out, int out_size, void* d_ws, size_t ws_size,
                              hipStream_t stream) {
  const float* node_vec  = (const float*)d_in[0];
  const float* node_mask = (const float*)d_in[1];
  const float* ln_scale  = (const float*)d_in[2];
  const float* ln_bias   = (const float*)d_in[3];
  const float* Wl        = (const float*)d_in[4];
  const float* bl        = (const float*)d_in[5];
  const float* Wr        = (const float*)d_in[6];
  const float* br        = (const float*)d_in[7];
  const float* Wo        = (const float*)d_in[8];
  const float* bo        = (const float*)d_in[9];
  float* out = (float*)d_out;

  float* left  = (float*)d_ws;                 // 256*32 floats
  float* right = left + A_N * C_N;             // 256*32 floats
  float* T     = right + A_N * C_N;            // 32*256*256 floats = 8 MB

  ln_proj_kernel<<<A_N, 256, 0, stream>>>(node_vec, node_mask, ln_scale, ln_bias,
                                          Wl, bl, Wr, br, left, right);
  compT_kernel<<<dim3(16, 32), 256, 0, stream>>>(right, Wo, T);
  out_kernel<<<dim3(4, A_N), 256, 0, stream>>>(left, T, bo, out);
}

// Round 4
// 114.697 us; speedup vs baseline: 1.1117x; 1.1117x over previous
//
#include <hip/hip_runtime.h>

#define A_N 256
#define F_N 256
#define C_N 32

// ---------------------------------------------------------------------------
// Kernel 1: LayerNorm + dual projections (+mask). One block per node.
// ---------------------------------------------------------------------------
__global__ __launch_bounds__(256) void ln_proj_kernel(
    const float* __restrict__ node_vec, const float* __restrict__ node_mask,
    const float* __restrict__ ln_scale, const float* __restrict__ ln_bias,
    const float* __restrict__ Wl, const float* __restrict__ bl,
    const float* __restrict__ Wr, const float* __restrict__ br,
    float* __restrict__ left, float* __restrict__ right) {
  const int a = blockIdx.x;
  const int t = threadIdx.x;
  __shared__ float sAct[F_N];
  __shared__ float sRed[8];
  __shared__ float sPl[8][C_N];
  __shared__ float sPr[8][C_N];

  float x = node_vec[a * F_N + t];

  // mean
  float s = x;
  for (int off = 32; off; off >>= 1) s += __shfl_down(s, off, 64);
  const int wave = t >> 6, lane = t & 63;
  if (lane == 0) sRed[wave] = s;
  __syncthreads();
  if (t == 0) sRed[4] = (sRed[0] + sRed[1] + sRed[2] + sRed[3]) * (1.0f / F_N);
  __syncthreads();
  const float mu = sRed[4];
  const float d = x - mu;

  // variance
  s = d * d;
  for (int off = 32; off; off >>= 1) s += __shfl_down(s, off, 64);
  if (lane == 0) sRed[wave] = s;
  __syncthreads();
  if (t == 0) {
    float v = (sRed[0] + sRed[1] + sRed[2] + sRed[3]) * (1.0f / F_N);
    sRed[5] = rsqrtf(v + 1e-5f);
  }
  __syncthreads();
  const float act = d * sRed[5] * ln_scale[t] + ln_bias[t];
  sAct[t] = act;
  __syncthreads();

  // projections: thread (seg, c) does a 32-long partial dot
  const int c = t & 31, seg = t >> 5;
  float pl = 0.f, pr = 0.f;
  const float* actp = &sAct[seg * 32];
#pragma unroll
  for (int j = 0; j < 32; ++j) {
    const float av = actp[j];
    const int widx = (seg * 32 + j) * C_N + c;
    pl = fmaf(av, Wl[widx], pl);
    pr = fmaf(av, Wr[widx], pr);
  }
  sPl[seg][c] = pl;
  sPr[seg][c] = pr;
  __syncthreads();
  if (t < C_N) {
    const float m = node_mask[a];
    float suml = bl[t], sumr = br[t];
#pragma unroll
    for (int sg = 0; sg < 8; ++sg) { suml += sPl[sg][t]; sumr += sPr[sg][t]; }
    left[a * C_N + t] = suml * m;
    right[a * C_N + t] = sumr * m;
  }
}

// ---------------------------------------------------------------------------
// Kernel 2: T[b][c][f] = sum_d right[b][d] * Wo[c*32+d][f]   (b-major layout!)
// grid: (16 b-tiles, 32 c). Wo row-block (32x256 = 32KB) in LDS.
// d-outer / b-inner with acc[16] registers: 544 LDS + 512 FMA per thread.
// ---------------------------------------------------------------------------
__global__ __launch_bounds__(256) void compT_kernel(
    const float* __restrict__ right, const float* __restrict__ Wo,
    float* __restrict__ T) {
  const int c = blockIdx.y;
  const int b0 = blockIdx.x * 16;
  const int f = threadIdx.x;
  __shared__ float sWo[C_N * F_N];  // 32 KB
  __shared__ float sR[16 * C_N];    // 2 KB

#pragma unroll
  for (int d = 0; d < C_N; ++d)
    sWo[d * F_N + f] = Wo[(c * C_N + d) * F_N + f];
  sR[f] = right[b0 * C_N + f];
  sR[256 + f] = right[b0 * C_N + 256 + f];
  __syncthreads();

  float acc[16];
#pragma unroll
  for (int b = 0; b < 16; ++b) acc[b] = 0.f;

#pragma unroll
  for (int d = 0; d < C_N; ++d) {
    const float wv = sWo[d * F_N + f];
#pragma unroll
    for (int b = 0; b < 16; ++b)
      acc[b] = fmaf(sR[b * C_N + d], wv, acc[b]);
  }

#pragma unroll
  for (int b = 0; b < 16; ++b)
    T[(size_t)(b0 + b) * (C_N * F_N) + c * F_N + f] = acc[b];
}

// ---------------------------------------------------------------------------
// Kernel 3: out[a][b][f] = bo[f] + sum_c left[a][c] * T[b][c][f]
// grid: (4 a-tiles of 64, 256 b). Thread = 4 consecutive f x 16 a-rows.
// float4 acc[16]: per c, 1 ds_read_b128 (T) + 16 broadcast b32 (left)
// feed 64 lane-FMAs  ->  544 LDS + 2048 FMA per thread (was 2560 LDS).
// ---------------------------------------------------------------------------
__global__ __launch_bounds__(256) void out_kernel(
    const float* __restrict__ left, const float* __restrict__ T,
    const float* __restrict__ bo, float* __restrict__ out) {
  const int b = blockIdx.y;
  const int a0 = blockIdx.x * 64;
  const int t = threadIdx.x;
  const int fq = t & 63;    // f-quad index: f = 4*fq .. 4*fq+3
  const int arow = t >> 6;  // 0..3, each handles 16 a-rows

  __shared__ float sT[C_N * F_N];  // [c][f] 32 KB
  __shared__ float sL[64 * C_N];   // [a][c]  8 KB

  // Stage T slice (contiguous 32 KB in [b][c][f] layout) + left tile, float4.
  float4* sT4 = (float4*)sT;
  const float4* Tg4 = (const float4*)(T + (size_t)b * (C_N * F_N));
#pragma unroll
  for (int k = 0; k < 8; ++k) sT4[k * 256 + t] = Tg4[k * 256 + t];
  float4* sL4 = (float4*)sL;
  const float4* Lg4 = (const float4*)(left + a0 * C_N);
#pragma unroll
  for (int k = 0; k < 2; ++k) sL4[k * 256 + t] = Lg4[k * 256 + t];
  const float4 bias4 = ((const float4*)bo)[fq];
  __syncthreads();

  float4 acc[16];
#pragma unroll
  for (int i = 0; i < 16; ++i) acc[i] = bias4;

  const float* sLrow = &sL[(arow * 16) * C_N];
#pragma unroll 8
  for (int c = 0; c < C_N; ++c) {
    const float4 tv = sT4[c * 64 + fq];
#pragma unroll
    for (int i = 0; i < 16; ++i) {
      const float lv = sLrow[i * C_N + c];
      acc[i].x = fmaf(lv, tv.x, acc[i].x);
      acc[i].y = fmaf(lv, tv.y, acc[i].y);
      acc[i].z = fmaf(lv, tv.z, acc[i].z);
      acc[i].w = fmaf(lv, tv.w, acc[i].w);
    }
  }

  float4* out4 = (float4*)out;
  const size_t rowq = (size_t)(A_N * F_N) / 4;  // float4 per a-row
#pragma unroll
  for (int i = 0; i < 16; ++i)
    out4[(size_t)(a0 + arow * 16 + i) * rowq + (size_t)b * 64 + fq] = acc[i];
}

extern "C" void kernel_launch(void* const* d_in, const int* in_sizes, int n_in,
                              void* d_out, int out_size, void* d_ws, size_t ws_size,
                              hipStream_t stream) {
  const float* node_vec  = (const float*)d_in[0];
  const float* node_mask = (const float*)d_in[1];
  const float* ln_scale  = (const float*)d_in[2];
  const float* ln_bias   = (const float*)d_in[3];
  const float* Wl        = (const float*)d_in[4];
  const float* bl        = (const float*)d_in[5];
  const float* Wr        = (const float*)d_in[6];
  const float* br        = (const float*)d_in[7];
  const float* Wo        = (const float*)d_in[8];
  const float* bo        = (const float*)d_in[9];
  float* out = (float*)d_out;

  float* left  = (float*)d_ws;                 // 256*32 floats
  float* right = left + A_N * C_N;             // 256*32 floats
  float* T     = right + A_N * C_N;            // 256*32*256 floats = 8 MB, [b][c][f]

  ln_proj_kernel<<<A_N, 256, 0, stream>>>(node_vec, node_mask, ln_scale, ln_bias,
                                          Wl, bl, Wr, br, left, right);
  compT_kernel<<<dim3(16, 32), 256, 0, stream>>>(right, Wo, T);
  out_kernel<<<dim3(4, A_N), 256, 0, stream>>>(left, T, bo, out);
}